// Round 9
// baseline (234.345 us; speedup 1.0000x reference)
//
#include <hip/hip_runtime.h>

#define EPS 1e-6f
#define LL 4096
#define HE 512

typedef __attribute__((ext_vector_type(8))) short short8;
typedef __attribute__((ext_vector_type(4))) float f32x4;

__device__ __forceinline__ unsigned short f2bf(float f) {
    union { float f; unsigned u; } v; v.f = f;
    unsigned r = v.u + 0x7FFFu + ((v.u >> 16) & 1u);  // RNE
    return (unsigned short)(r >> 16);
}
__device__ __forceinline__ float bf2f(unsigned short s) {
    union { unsigned u; float f; } v; v.u = ((unsigned)s) << 16;
    return v.f;
}
// async global->LDS, 16B per lane; LDS dest = wave-uniform base + lane*16
__device__ __forceinline__ void gl16(const unsigned short* g, unsigned short* l) {
    __builtin_amdgcn_global_load_lds(
        (const __attribute__((address_space(1))) unsigned int*)(const void*)g,
        (__attribute__((address_space(3))) unsigned int*)(void*)l,
        16, 0, 0);
}

// ---- k1: q -> Vb + Vt + stat partials; 32-row tiles, lean phases --------
// grid 2048 (16 b x 128 slabs of 32 rows). LDS union: stats 16KB / transpose
// 36KB ([512 n][36 l-swizzled]). All-thread phases, b64 LDS ops, ~80 VGPR.
__global__ __launch_bounds__(256) void k1_fuse3(const float* __restrict__ q,
        unsigned short* __restrict__ Vb, unsigned short* __restrict__ Vt,
        float* __restrict__ ps, float* __restrict__ pq) {
    __shared__ __attribute__((aligned(16))) char smem[512 * 36 * 2];
    float (*lds_s)[512] = (float (*)[512])smem;                      // 8KB
    float (*lds_q)[512] = (float (*)[512])(smem + 8192);             // 8KB
    unsigned short (*ldsT)[36] = (unsigned short (*)[36])smem;       // 36KB (reused)
    int blk = blockIdx.x;
    int b = blk >> 7, slab = blk & 127;
    int t = threadIdx.x;
    int w = t >> 6, oct = t & 63;
    int row0 = slab * 32 + w * 8;
    const float* qb = q + ((size_t)b * LL + row0) * HE + oct * 8;
    unsigned short* vb = Vb + ((size_t)b * LL + row0) * HE + oct * 8;
    short8 rows8[8];
    float s[8] = {}, qq[8] = {};
    #pragma unroll
    for (int r = 0; r < 8; r++) {
        float4 v0 = *(const float4*)(qb + (size_t)r * HE);
        float4 v1 = *(const float4*)(qb + (size_t)r * HE + 4);
        unsigned short e[8] = {f2bf(v0.x), f2bf(v0.y), f2bf(v0.z), f2bf(v0.w),
                               f2bf(v1.x), f2bf(v1.y), f2bf(v1.z), f2bf(v1.w)};
        short8 w8;
        #pragma unroll
        for (int c = 0; c < 8; c++) {
            w8[c] = (short)e[c];
            float x = bf2f(e[c]);
            s[c] += x; qq[c] += x * x;
        }
        rows8[r] = w8;
        *(short8*)(vb + (size_t)r * HE) = w8;
    }
    // stats partials (32-row slab partial per column)
    #pragma unroll
    for (int c = 0; c < 8; c++) {
        lds_s[w][oct * 8 + c] = s[c];
        lds_q[w][oct * 8 + c] = qq[c];
    }
    __syncthreads();
    #pragma unroll
    for (int h = 0; h < 2; h++) {
        int col = h * 256 + t;
        float ss = lds_s[0][col] + lds_s[1][col] + lds_s[2][col] + lds_s[3][col];
        float sq = lds_q[0][col] + lds_q[1][col] + lds_q[2][col] + lds_q[3][col];
        ps[(size_t)slab * 8192 + b * 512 + col] = ss;
        pq[(size_t)slab * 8192 + b * 512 + col] = sq;
    }
    __syncthreads();   // stats reads done; reuse LDS for transpose
    // transpose write: n1 = oct*8+c, l-positions (w*8+g*4) ^ 4*(oct&7)
    int swz = (oct & 7) * 4;
    #pragma unroll
    for (int c = 0; c < 8; c++) {
        int n1 = oct * 8 + c;
        #pragma unroll
        for (int g = 0; g < 2; g++) {
            int lp = (w * 8 + g * 4) ^ swz;
            uint2 dv;
            dv.x = (unsigned)(unsigned short)rows8[g*4+0][c]
                 | ((unsigned)(unsigned short)rows8[g*4+1][c] << 16);
            dv.y = (unsigned)(unsigned short)rows8[g*4+2][c]
                 | ((unsigned)(unsigned short)rows8[g*4+3][c] << 16);
            *(uint2*)&ldsT[n1][lp] = dv;
        }
    }
    __syncthreads();
    // readout: 2 n-rows per thread, 32 l each -> 4 uint4 stores
    #pragma unroll
    for (int i = 0; i < 2; i++) {
        int n = t + i * 256;
        int nswz = ((n >> 3) & 7) * 4;
        uint2 ck[8];
        #pragma unroll
        for (int k = 0; k < 8; k++)
            ck[k] = *(const uint2*)&ldsT[n][(k * 4) ^ nswz];
        unsigned short* dst = Vt + ((size_t)b * HE + n) * LL + slab * 32;
        #pragma unroll
        for (int k = 0; k < 4; k++) {
            uint4 uv;
            uv.x = ck[2*k].x; uv.y = ck[2*k].y;
            uv.z = ck[2*k+1].x; uv.w = ck[2*k+1].y;
            *(uint4*)(dst + k * 8) = uv;
        }
    }
}

// ---- k2: reduce 128 slab-partials -> sumV, cvec, invn -------------------
__global__ __launch_bounds__(256) void k2_reduce(const float* __restrict__ ps,
        const float* __restrict__ pq, float* __restrict__ sumV,
        float* __restrict__ cvec, float* __restrict__ invn) {
    int i = blockIdx.x * 256 + threadIdx.x;   // 0..8191 = b*512 + n
    float s = 0.f, qq = 0.f;
    #pragma unroll 8
    for (int lt = 0; lt < 128; lt++) {
        s  += ps[(size_t)lt * 8192 + i];
        qq += pq[(size_t)lt * 8192 + i];
    }
    float inv = 1.0f / sqrtf(qq);
    sumV[i] = s;
    invn[i] = inv;
    cvec[i] = (s * inv + EPS) * inv;
}

// ---- k3: dvec[b,l] = sum_n Vb[l,n]*cvec[n]  (GEMV) ----------------------
__global__ __launch_bounds__(256) void k3_dvec(const unsigned short* __restrict__ Vb,
        const float* __restrict__ cvec, float* __restrict__ dvec) {
    int blk = blockIdx.x;
    int b = blk >> 7, lblk = blk & 127;
    int t = threadIdx.x;
    int lloc = t >> 3, j = t & 7;
    int l = lblk * 32 + lloc;
    const unsigned short* rowp = Vb + ((size_t)b * LL + l) * HE + j * 64;
    const float* cp = cvec + b * HE + j * 64;
    float d = 0.f;
    #pragma unroll
    for (int g = 0; g < 8; g++) {
        short8 v = *(const short8*)(rowp + g * 8);
        float4 c0 = *(const float4*)(cp + g * 8);
        float4 c1 = *(const float4*)(cp + g * 8 + 4);
        d += bf2f((unsigned short)v[0]) * c0.x + bf2f((unsigned short)v[1]) * c0.y
           + bf2f((unsigned short)v[2]) * c0.z + bf2f((unsigned short)v[3]) * c0.w
           + bf2f((unsigned short)v[4]) * c1.x + bf2f((unsigned short)v[5]) * c1.y
           + bf2f((unsigned short)v[6]) * c1.z + bf2f((unsigned short)v[7]) * c1.w;
    }
    d += __shfl_xor(d, 1); d += __shfl_xor(d, 2); d += __shfl_xor(d, 4);
    if (j == 0) dvec[(size_t)b * LL + l] = d;
}

// ---- k4: Gram partials (bf16, [ml][nl]), split-K=8, symmetric pairs -----
// r5-proven: gl16 from Vt, 2-phase double-buffered, counted vmcnt.
__global__ __launch_bounds__(256) void k4_gram(const unsigned short* __restrict__ Vt,
        unsigned short* __restrict__ Gp) {
    __shared__ __attribute__((aligned(16))) unsigned short la[2][128][64];
    __shared__ __attribute__((aligned(16))) unsigned short lb[2][128][64];
    int cpx = gridDim.x >> 3;
    int blk = ((int)blockIdx.x & 7) * cpx + ((int)blockIdx.x >> 3);  // XCD swizzle
    int b = blk / 80;
    int rem = blk - b * 80;
    int pair = rem >> 3, split = rem & 7;
    int nt = (pair < 4) ? 0 : (pair < 7) ? 1 : (pair < 9) ? 2 : 3;
    int off = (nt * (9 - nt)) >> 1;
    int mt = nt + pair - off;
    bool diag = (nt == mt);
    int N0 = nt * 128, M0 = mt * 128;
    int t = threadIdx.x;
    int w = t >> 6, lane = t & 63;
    int wr = w >> 1, wc = w & 1;
    int rl = lane >> 3;                    // row-in-8 for staging
    int cl = ((lane & 7) ^ rl) << 3;       // pre-swizzled source chunk (elems)
    int lr = lane & 15, q4 = lane >> 4;
    int ch0 = (q4 ^ (lane & 7)) << 3;      // swizzled read col, ks=0 (elems)
    const unsigned short* pa = Vt + ((size_t)b * HE + N0) * LL + split * 512;
    const unsigned short* pb = Vt + ((size_t)b * HE + M0) * LL + split * 512;
    f32x4 acc[4][4] = {};

#define STAGE4(B, KB) do { \
    int _k0 = (KB) * 64; \
    _Pragma("unroll") \
    for (int p = 0; p < 4; p++) { \
        int r0 = p * 32 + w * 8; \
        gl16(pa + (size_t)(r0 + rl) * LL + _k0 + cl, &la[B][r0][0]); \
        if (!diag) gl16(pb + (size_t)(r0 + rl) * LL + _k0 + cl, &lb[B][r0][0]); \
    } } while (0)

    STAGE4(0, 0);  // prologue
    #pragma unroll
    for (int kb = 0; kb < 8; kb++) {
        int cur = kb & 1;
        if (kb < 7) {
            STAGE4(cur ^ 1, kb + 1);
            if (diag) { asm volatile("s_waitcnt vmcnt(4)" ::: "memory"); }
            else      { asm volatile("s_waitcnt vmcnt(8)" ::: "memory"); }
        } else {
            asm volatile("s_waitcnt vmcnt(0)" ::: "memory");
        }
        __builtin_amdgcn_s_barrier();
        const unsigned short (*A)[64] = la[cur];
        const unsigned short (*Bp)[64] = diag ? la[cur] : lb[cur];
        #pragma unroll
        for (int ks = 0; ks < 2; ks++) {
            int colA = ch0 ^ (ks << 5);
            short8 af[4], bfr[4];
            #pragma unroll
            for (int i = 0; i < 4; i++)
                af[i] = *(const short8*)&A[wr*64 + i*16 + lr][colA];
            #pragma unroll
            for (int j = 0; j < 4; j++)
                bfr[j] = *(const short8*)&Bp[wc*64 + j*16 + lr][colA];
            #pragma unroll
            for (int i = 0; i < 4; i++)
                #pragma unroll
                for (int j = 0; j < 4; j++)
                    acc[i][j] = __builtin_amdgcn_mfma_f32_16x16x32_bf16(af[i], bfr[j], acc[i][j], 0, 0, 0);
        }
        __builtin_amdgcn_s_barrier();
    }
#undef STAGE4
    // store bf16 partials, layout [ml*128 + nl] -> ushort4 along n
    size_t tbase = ((size_t)(b * 10 + pair) * 8 + split) * 16384;
    #pragma unroll
    for (int i = 0; i < 4; i++) {
        int nb = wr*64 + i*16 + q4*4;
        #pragma unroll
        for (int j = 0; j < 4; j++) {
            int ml = wc*64 + j*16 + lr;
            ushort4 wv;
            wv.x = f2bf(acc[i][j][0]); wv.y = f2bf(acc[i][j][1]);
            wv.z = f2bf(acc[i][j][2]); wv.w = f2bf(acc[i][j][3]);
            *(ushort4*)&Gp[tbase + (size_t)ml * 128 + nb] = wv;
        }
    }
}

// ---- k5: sum splits, scale by invn outer, write KQb both orientations ---
__global__ __launch_bounds__(256) void k5_reduce(const unsigned short* __restrict__ Gp,
        const float* __restrict__ invn, unsigned short* __restrict__ KQb) {
    __shared__ unsigned short lds_t[128][130];
    int blk = blockIdx.x;
    int b = blk / 10, pair = blk % 10;
    int nt = (pair < 4) ? 0 : (pair < 7) ? 1 : (pair < 9) ? 2 : 3;
    int off = (nt * (9 - nt)) >> 1;
    int mt = nt + pair - off;
    int N0 = nt * 128, M0 = mt * 128;
    int t = threadIdx.x;
    const unsigned short* gp = Gp + ((size_t)(b * 10 + pair) * 8) * 16384;
    const float* inb = invn + (size_t)b * HE;
    #pragma unroll 2
    for (int e = 0; e < 32; e++) {
        int idx = e * 512 + t * 2;           // [ml][nl] pairs
        int ml = idx >> 7, nl = idx & 127;
        float s0 = 0.f, s1 = 0.f;
        #pragma unroll
        for (int sp = 0; sp < 8; sp++) {
            unsigned g2 = *(const unsigned*)&gp[(size_t)sp * 16384 + idx];
            s0 += bf2f((unsigned short)(g2 & 0xFFFF));
            s1 += bf2f((unsigned short)(g2 >> 16));
        }
        float im = inb[M0 + ml];
        ushort2 v;
        v.x = f2bf(s0 * inb[N0 + nl] * im);
        v.y = f2bf(s1 * inb[N0 + nl + 1] * im);
        *(ushort2*)&KQb[((size_t)b * HE + M0 + ml) * HE + N0 + nl] = v;
        *(ushort2*)&lds_t[ml][nl] = v;
    }
    __syncthreads();
    #pragma unroll 2
    for (int e = 0; e < 32; e++) {
        int idx = e * 512 + t * 2;
        int nl = idx >> 7, ml = idx & 127;   // transposed roles
        ushort2 v;
        v.x = lds_t[ml][nl];
        v.y = lds_t[ml + 1][nl];
        *(ushort2*)&KQb[((size_t)b * HE + N0 + nl) * HE + M0 + ml] = v;
    }
}

// ---- k6: part GEMM (KQb x Vb) + tailor/sumV/residual epilogue -----------
// 2-phase double-buffered: counted vmcnt + raw s_barrier
__global__ __launch_bounds__(256) void k6_part(const unsigned short* __restrict__ KQb,
        const unsigned short* __restrict__ Vb, const float* __restrict__ dvec,
        const float* __restrict__ sumV, const float* __restrict__ gamma,
        float* __restrict__ out) {
    __shared__ __attribute__((aligned(16))) unsigned short la[2][128][64];
    __shared__ __attribute__((aligned(16))) unsigned short lb[2][128][64];
    int cpx = gridDim.x >> 3;
    int blk = ((int)blockIdx.x & 7) * cpx + ((int)blockIdx.x >> 3);  // XCD swizzle
    int b = blk >> 7, mt = (blk >> 5) & 3, lt = blk & 31;
    int M0 = mt * 128, L0 = lt * 128;
    int t = threadIdx.x;
    int w = t >> 6, lane = t & 63;
    int wr = w >> 1, wc = w & 1;
    int rl = lane >> 3;
    int cl = ((lane & 7) ^ rl) << 3;
    int lr = lane & 15, q4 = lane >> 4;
    int ch0 = (q4 ^ (lane & 7)) << 3;
    const unsigned short* pa = KQb + ((size_t)b * HE + M0) * HE;
    const unsigned short* pb = Vb + ((size_t)b * LL + L0) * HE;
    float gma = gamma[0];   // hoisted above prologue so vmcnt counting stays exact
    f32x4 acc[4][4] = {};

#define STAGE6(B, KB) do { \
    int _k0 = (KB) * 64; \
    _Pragma("unroll") \
    for (int p = 0; p < 4; p++) { \
        int r0 = p * 32 + w * 8; \
        gl16(pa + (size_t)(r0 + rl) * HE + _k0 + cl, &la[B][r0][0]); \
        gl16(pb + (size_t)(r0 + rl) * HE + _k0 + cl, &lb[B][r0][0]); \
    } } while (0)

    STAGE6(0, 0);  // prologue
    #pragma unroll
    for (int kb = 0; kb < 8; kb++) {
        int cur = kb & 1;
        if (kb < 7) {
            STAGE6(cur ^ 1, kb + 1);
            asm volatile("s_waitcnt vmcnt(8)" ::: "memory");
        } else {
            asm volatile("s_waitcnt vmcnt(0)" ::: "memory");
        }
        __builtin_amdgcn_s_barrier();
        #pragma unroll
        for (int ks = 0; ks < 2; ks++) {
            int colA = ch0 ^ (ks << 5);
            short8 af[4], bfr[4];
            #pragma unroll
            for (int i = 0; i < 4; i++)
                af[i] = *(const short8*)&la[cur][wr*64 + i*16 + lr][colA];
            #pragma unroll
            for (int j = 0; j < 4; j++)
                bfr[j] = *(const short8*)&lb[cur][wc*64 + j*16 + lr][colA];
            #pragma unroll
            for (int i = 0; i < 4; i++)
                #pragma unroll
                for (int j = 0; j < 4; j++)
                    acc[i][j] = __builtin_amdgcn_mfma_f32_16x16x32_bf16(af[i], bfr[j], acc[i][j], 0, 0, 0);
        }
        __builtin_amdgcn_s_barrier();
    }
#undef STAGE6
    #pragma unroll
    for (int j = 0; j < 4; j++) {
        int lglob = L0 + wc*64 + j*16 + lr;
        float dt = dvec[(size_t)b * LL + lglob];
        float tailor = 1.0f / (512.0f + dt);
        #pragma unroll
        for (int i = 0; i < 4; i++) {
            int m4 = M0 + wr*64 + i*16 + q4*4;
            size_t ofs = ((size_t)b * LL + lglob) * HE + m4;
            ushort4 rv = *(const ushort4*)(Vb + ((size_t)b * LL + lglob) * HE + m4);
            float4 vs = *(const float4*)(sumV + (size_t)b * HE + m4);
            float4 o;
            o.x = bf2f(rv.x) + gma * (vs.x + acc[i][j][0]) * tailor;
            o.y = bf2f(rv.y) + gma * (vs.y + acc[i][j][1]) * tailor;
            o.z = bf2f(rv.z) + gma * (vs.z + acc[i][j][2]) * tailor;
            o.w = bf2f(rv.w) + gma * (vs.w + acc[i][j][3]) * tailor;
            *(float4*)(out + ofs) = o;
        }
    }
}

extern "C" void kernel_launch(void* const* d_in, const int* in_sizes, int n_in,
                              void* d_out, int out_size, void* d_ws, size_t ws_size,
                              hipStream_t stream) {
    const float* q     = (const float*)d_in[0];
    const float* gamma = (const float*)d_in[4];
    float* out = (float*)d_out;
    char* ws = (char*)d_ws;
    // ws layout (~177 MiB; proven to fit)
    float* sumV  = (float*)(ws);                          // 32 KiB
    float* cvec  = (float*)(ws + 65536);                  // 32 KiB
    float* invn  = (float*)(ws + 98304);                  // 32 KiB
    float* dvec  = (float*)(ws + 131072);                 // 256 KiB
    unsigned short* KQb = (unsigned short*)(ws + 524288);      // 8 MiB
    unsigned short* Vt  = (unsigned short*)(ws + 8912896);     // 64 MiB
    unsigned short* Vb  = (unsigned short*)(ws + 76021760);    // 64 MiB
    unsigned short* Gp  = (unsigned short*)(ws + 143130624);   // 40 MiB
    // stat partials live in d_out's head (8 MiB), consumed by k2 before k6
    float* ps = (float*)d_out;                            // 4 MiB (128 x 8192)
    float* pq = (float*)d_out + 1048576;                  // 4 MiB

    k1_fuse3 <<<2048, 256, 0, stream>>>(q, Vb, Vt, ps, pq);
    k2_reduce<<<32,   256, 0, stream>>>(ps, pq, sumV, cvec, invn);
    k3_dvec  <<<2048, 256, 0, stream>>>(Vb, cvec, dvec);
    k4_gram  <<<1280, 256, 0, stream>>>(Vt, Gp);
    k5_reduce<<<160,  256, 0, stream>>>(Gp, invn, KQb);
    k6_part  <<<2048, 256, 0, stream>>>(KQb, Vb, dvec, sumV, gamma, out);
}

// Round 10
// 209.678 us; speedup vs baseline: 1.1176x; 1.1176x over previous
//
#include <hip/hip_runtime.h>

#define EPS 1e-6f
#define LL 4096
#define HE 512

typedef __attribute__((ext_vector_type(8))) short short8;
typedef __attribute__((ext_vector_type(4))) float f32x4;

__device__ __forceinline__ unsigned short f2bf(float f) {
    union { float f; unsigned u; } v; v.f = f;
    unsigned r = v.u + 0x7FFFu + ((v.u >> 16) & 1u);  // RNE
    return (unsigned short)(r >> 16);
}
__device__ __forceinline__ float bf2f(unsigned short s) {
    union { unsigned u; float f; } v; v.u = ((unsigned)s) << 16;
    return v.f;
}
// async global->LDS, 16B per lane; LDS dest = wave-uniform base + lane*16
__device__ __forceinline__ void gl16(const unsigned short* g, unsigned short* l) {
    __builtin_amdgcn_global_load_lds(
        (const __attribute__((address_space(1))) unsigned int*)(const void*)g,
        (__attribute__((address_space(3))) unsigned int*)(void*)l,
        16, 0, 0);
}

// ---- k1: q -> Vb + Vt + stat partials; 256l x 128n tiles, big chunks ----
// All global chunks >= 256 B. One barrier. Transpose via 64KB uint LDS
// [128 n][128 l-pair], swizzle col ^= (n & 30).
__global__ __launch_bounds__(256) void k1_fuse4(const float* __restrict__ q,
        unsigned short* __restrict__ Vb, unsigned short* __restrict__ Vt,
        float* __restrict__ ps, float* __restrict__ pq) {
    __shared__ unsigned ldsT[128][128];   // 64 KB
    int blk = blockIdx.x;
    int b = blk >> 6, lt = (blk >> 2) & 15, ng = blk & 3;
    int t = threadIdx.x;
    int n4 = t & 31;          // float4 index within 128-n tile
    int rg = t >> 5;          // 0..7
    const float* qbase = q + ((size_t)b * LL + lt * 256) * HE + ng * 128 + n4 * 4;
    unsigned short* vbase = Vb + ((size_t)b * LL + lt * 256) * HE + ng * 128 + n4 * 4;
    float s0 = 0, s1 = 0, s2 = 0, s3 = 0, q0 = 0, q1 = 0, q2 = 0, q3 = 0;
    #pragma unroll
    for (int p = 0; p < 16; p++) {
        int c0 = p * 8 + rg;      // l-pair column 0..127
        int l0 = c0 * 2;
        const float* rp = qbase + (size_t)l0 * HE;
        float4 va = *(const float4*)rp;
        float4 vb2 = *(const float4*)(rp + HE);
        unsigned short ea[4] = {f2bf(va.x), f2bf(va.y), f2bf(va.z), f2bf(va.w)};
        unsigned short eb[4] = {f2bf(vb2.x), f2bf(vb2.y), f2bf(vb2.z), f2bf(vb2.w)};
        ushort4 ua; ua.x = ea[0]; ua.y = ea[1]; ua.z = ea[2]; ua.w = ea[3];
        ushort4 ub; ub.x = eb[0]; ub.y = eb[1]; ub.z = eb[2]; ub.w = eb[3];
        *(ushort4*)(vbase + (size_t)l0 * HE) = ua;
        *(ushort4*)(vbase + (size_t)(l0 + 1) * HE) = ub;
        float xa0 = bf2f(ea[0]), xa1 = bf2f(ea[1]), xa2 = bf2f(ea[2]), xa3 = bf2f(ea[3]);
        float xb0 = bf2f(eb[0]), xb1 = bf2f(eb[1]), xb2 = bf2f(eb[2]), xb3 = bf2f(eb[3]);
        s0 += xa0 + xb0; q0 += xa0 * xa0 + xb0 * xb0;
        s1 += xa1 + xb1; q1 += xa1 * xa1 + xb1 * xb1;
        s2 += xa2 + xb2; q2 += xa2 * xa2 + xb2 * xb2;
        s3 += xa3 + xb3; q3 += xa3 * xa3 + xb3 * xb3;
        #pragma unroll
        for (int j = 0; j < 4; j++) {
            int nl = n4 * 4 + j;
            unsigned uv = (unsigned)ea[j] | ((unsigned)eb[j] << 16);
            ldsT[nl][c0 ^ (nl & 30)] = uv;
        }
    }
    // per-thread stat partials (float4, coalesced) into d_out-head scratch
    {
        size_t pidx = ((size_t)(b * 16 + lt) * 8 + rg) * 512 + ng * 128 + n4 * 4;
        float4 sv; sv.x = s0; sv.y = s1; sv.z = s2; sv.w = s3;
        float4 qv; qv.x = q0; qv.y = q1; qv.z = q2; qv.w = q3;
        *(float4*)(ps + pidx) = sv;
        *(float4*)(pq + pidx) = qv;
    }
    __syncthreads();
    // readout: wave w covers n = w*32..w*32+31; lane = l-chunk (4 l = 8 B)
    int w = t >> 6, lane = t & 63;
    #pragma unroll
    for (int i = 0; i < 32; i++) {
        int nl = w * 32 + i;
        uint2 d = *(const uint2*)&ldsT[nl][(2 * lane) ^ (nl & 30)];
        unsigned short* dst = Vt + ((size_t)b * HE + ng * 128 + nl) * LL + lt * 256 + lane * 4;
        *(uint2*)dst = d;
    }
}

// ---- k2: reduce 128 slab-partials (b-major) -> sumV, cvec, invn ---------
__global__ __launch_bounds__(256) void k2_reduce(const float* __restrict__ ps,
        const float* __restrict__ pq, float* __restrict__ sumV,
        float* __restrict__ cvec, float* __restrict__ invn) {
    int i = blockIdx.x * 256 + threadIdx.x;   // 0..8191 = b*512 + n
    int b = i >> 9, n = i & 511;
    const float* pb = ps + (size_t)b * 65536 + n;
    const float* qb = pq + (size_t)b * 65536 + n;
    float s = 0.f, qq = 0.f;
    #pragma unroll 8
    for (int sl = 0; sl < 128; sl++) {
        s  += pb[sl * 512];
        qq += qb[sl * 512];
    }
    float inv = 1.0f / sqrtf(qq);
    sumV[i] = s;
    invn[i] = inv;
    cvec[i] = (s * inv + EPS) * inv;
}

// ---- k3: dvec[b,l] = sum_n Vb[l,n]*cvec[n]  (GEMV) ----------------------
__global__ __launch_bounds__(256) void k3_dvec(const unsigned short* __restrict__ Vb,
        const float* __restrict__ cvec, float* __restrict__ dvec) {
    int blk = blockIdx.x;
    int b = blk >> 7, lblk = blk & 127;
    int t = threadIdx.x;
    int lloc = t >> 3, j = t & 7;
    int l = lblk * 32 + lloc;
    const unsigned short* rowp = Vb + ((size_t)b * LL + l) * HE + j * 64;
    const float* cp = cvec + b * HE + j * 64;
    float d = 0.f;
    #pragma unroll
    for (int g = 0; g < 8; g++) {
        short8 v = *(const short8*)(rowp + g * 8);
        float4 c0 = *(const float4*)(cp + g * 8);
        float4 c1 = *(const float4*)(cp + g * 8 + 4);
        d += bf2f((unsigned short)v[0]) * c0.x + bf2f((unsigned short)v[1]) * c0.y
           + bf2f((unsigned short)v[2]) * c0.z + bf2f((unsigned short)v[3]) * c0.w
           + bf2f((unsigned short)v[4]) * c1.x + bf2f((unsigned short)v[5]) * c1.y
           + bf2f((unsigned short)v[6]) * c1.z + bf2f((unsigned short)v[7]) * c1.w;
    }
    d += __shfl_xor(d, 1); d += __shfl_xor(d, 2); d += __shfl_xor(d, 4);
    if (j == 0) dvec[(size_t)b * LL + l] = d;
}

// ---- k4: Gram partials (bf16, [ml][nl]), split-K=8, symmetric pairs -----
// r5-proven: gl16 from Vt, 2-phase double-buffered, counted vmcnt.
__global__ __launch_bounds__(256) void k4_gram(const unsigned short* __restrict__ Vt,
        unsigned short* __restrict__ Gp) {
    __shared__ __attribute__((aligned(16))) unsigned short la[2][128][64];
    __shared__ __attribute__((aligned(16))) unsigned short lb[2][128][64];
    int cpx = gridDim.x >> 3;
    int blk = ((int)blockIdx.x & 7) * cpx + ((int)blockIdx.x >> 3);  // XCD swizzle
    int b = blk / 80;
    int rem = blk - b * 80;
    int pair = rem >> 3, split = rem & 7;
    int nt = (pair < 4) ? 0 : (pair < 7) ? 1 : (pair < 9) ? 2 : 3;
    int off = (nt * (9 - nt)) >> 1;
    int mt = nt + pair - off;
    bool diag = (nt == mt);
    int N0 = nt * 128, M0 = mt * 128;
    int t = threadIdx.x;
    int w = t >> 6, lane = t & 63;
    int wr = w >> 1, wc = w & 1;
    int rl = lane >> 3;                    // row-in-8 for staging
    int cl = ((lane & 7) ^ rl) << 3;       // pre-swizzled source chunk (elems)
    int lr = lane & 15, q4 = lane >> 4;
    int ch0 = (q4 ^ (lane & 7)) << 3;      // swizzled read col, ks=0 (elems)
    const unsigned short* pa = Vt + ((size_t)b * HE + N0) * LL + split * 512;
    const unsigned short* pb = Vt + ((size_t)b * HE + M0) * LL + split * 512;
    f32x4 acc[4][4] = {};

#define STAGE4(B, KB) do { \
    int _k0 = (KB) * 64; \
    _Pragma("unroll") \
    for (int p = 0; p < 4; p++) { \
        int r0 = p * 32 + w * 8; \
        gl16(pa + (size_t)(r0 + rl) * LL + _k0 + cl, &la[B][r0][0]); \
        if (!diag) gl16(pb + (size_t)(r0 + rl) * LL + _k0 + cl, &lb[B][r0][0]); \
    } } while (0)

    STAGE4(0, 0);  // prologue
    #pragma unroll
    for (int kb = 0; kb < 8; kb++) {
        int cur = kb & 1;
        if (kb < 7) {
            STAGE4(cur ^ 1, kb + 1);
            if (diag) { asm volatile("s_waitcnt vmcnt(4)" ::: "memory"); }
            else      { asm volatile("s_waitcnt vmcnt(8)" ::: "memory"); }
        } else {
            asm volatile("s_waitcnt vmcnt(0)" ::: "memory");
        }
        __builtin_amdgcn_s_barrier();
        const unsigned short (*A)[64] = la[cur];
        const unsigned short (*Bp)[64] = diag ? la[cur] : lb[cur];
        #pragma unroll
        for (int ks = 0; ks < 2; ks++) {
            int colA = ch0 ^ (ks << 5);
            short8 af[4], bfr[4];
            #pragma unroll
            for (int i = 0; i < 4; i++)
                af[i] = *(const short8*)&A[wr*64 + i*16 + lr][colA];
            #pragma unroll
            for (int j = 0; j < 4; j++)
                bfr[j] = *(const short8*)&Bp[wc*64 + j*16 + lr][colA];
            #pragma unroll
            for (int i = 0; i < 4; i++)
                #pragma unroll
                for (int j = 0; j < 4; j++)
                    acc[i][j] = __builtin_amdgcn_mfma_f32_16x16x32_bf16(af[i], bfr[j], acc[i][j], 0, 0, 0);
        }
        __builtin_amdgcn_s_barrier();
    }
#undef STAGE4
    // store bf16 partials, layout [ml*128 + nl] -> ushort4 along n
    size_t tbase = ((size_t)(b * 10 + pair) * 8 + split) * 16384;
    #pragma unroll
    for (int i = 0; i < 4; i++) {
        int nb = wr*64 + i*16 + q4*4;
        #pragma unroll
        for (int j = 0; j < 4; j++) {
            int ml = wc*64 + j*16 + lr;
            ushort4 wv;
            wv.x = f2bf(acc[i][j][0]); wv.y = f2bf(acc[i][j][1]);
            wv.z = f2bf(acc[i][j][2]); wv.w = f2bf(acc[i][j][3]);
            *(ushort4*)&Gp[tbase + (size_t)ml * 128 + nb] = wv;
        }
    }
}

// ---- k5: sum splits, scale by invn outer, write KQb both orientations ---
__global__ __launch_bounds__(256) void k5_reduce(const unsigned short* __restrict__ Gp,
        const float* __restrict__ invn, unsigned short* __restrict__ KQb) {
    __shared__ unsigned short lds_t[128][130];
    int blk = blockIdx.x;
    int b = blk / 10, pair = blk % 10;
    int nt = (pair < 4) ? 0 : (pair < 7) ? 1 : (pair < 9) ? 2 : 3;
    int off = (nt * (9 - nt)) >> 1;
    int mt = nt + pair - off;
    int N0 = nt * 128, M0 = mt * 128;
    int t = threadIdx.x;
    const unsigned short* gp = Gp + ((size_t)(b * 10 + pair) * 8) * 16384;
    const float* inb = invn + (size_t)b * HE;
    #pragma unroll 2
    for (int e = 0; e < 32; e++) {
        int idx = e * 512 + t * 2;           // [ml][nl] pairs
        int ml = idx >> 7, nl = idx & 127;
        float s0 = 0.f, s1 = 0.f;
        #pragma unroll
        for (int sp = 0; sp < 8; sp++) {
            unsigned g2 = *(const unsigned*)&gp[(size_t)sp * 16384 + idx];
            s0 += bf2f((unsigned short)(g2 & 0xFFFF));
            s1 += bf2f((unsigned short)(g2 >> 16));
        }
        float im = inb[M0 + ml];
        ushort2 v;
        v.x = f2bf(s0 * inb[N0 + nl] * im);
        v.y = f2bf(s1 * inb[N0 + nl + 1] * im);
        *(ushort2*)&KQb[((size_t)b * HE + M0 + ml) * HE + N0 + nl] = v;
        *(ushort2*)&lds_t[ml][nl] = v;
    }
    __syncthreads();
    #pragma unroll 2
    for (int e = 0; e < 32; e++) {
        int idx = e * 512 + t * 2;
        int nl = idx >> 7, ml = idx & 127;   // transposed roles
        ushort2 v;
        v.x = lds_t[ml][nl];
        v.y = lds_t[ml + 1][nl];
        *(ushort2*)&KQb[((size_t)b * HE + N0 + nl) * HE + M0 + ml] = v;
    }
}

// ---- k6: part GEMM (KQb x Vb) + tailor/sumV/residual epilogue -----------
// 2-phase double-buffered: counted vmcnt + raw s_barrier
__global__ __launch_bounds__(256) void k6_part(const unsigned short* __restrict__ KQb,
        const unsigned short* __restrict__ Vb, const float* __restrict__ dvec,
        const float* __restrict__ sumV, const float* __restrict__ gamma,
        float* __restrict__ out) {
    __shared__ __attribute__((aligned(16))) unsigned short la[2][128][64];
    __shared__ __attribute__((aligned(16))) unsigned short lb[2][128][64];
    int cpx = gridDim.x >> 3;
    int blk = ((int)blockIdx.x & 7) * cpx + ((int)blockIdx.x >> 3);  // XCD swizzle
    int b = blk >> 7, mt = (blk >> 5) & 3, lt = blk & 31;
    int M0 = mt * 128, L0 = lt * 128;
    int t = threadIdx.x;
    int w = t >> 6, lane = t & 63;
    int wr = w >> 1, wc = w & 1;
    int rl = lane >> 3;
    int cl = ((lane & 7) ^ rl) << 3;
    int lr = lane & 15, q4 = lane >> 4;
    int ch0 = (q4 ^ (lane & 7)) << 3;
    const unsigned short* pa = KQb + ((size_t)b * HE + M0) * HE;
    const unsigned short* pb = Vb + ((size_t)b * LL + L0) * HE;
    float gma = gamma[0];   // hoisted above prologue so vmcnt counting stays exact
    f32x4 acc[4][4] = {};

#define STAGE6(B, KB) do { \
    int _k0 = (KB) * 64; \
    _Pragma("unroll") \
    for (int p = 0; p < 4; p++) { \
        int r0 = p * 32 + w * 8; \
        gl16(pa + (size_t)(r0 + rl) * HE + _k0 + cl, &la[B][r0][0]); \
        gl16(pb + (size_t)(r0 + rl) * HE + _k0 + cl, &lb[B][r0][0]); \
    } } while (0)

    STAGE6(0, 0);  // prologue
    #pragma unroll
    for (int kb = 0; kb < 8; kb++) {
        int cur = kb & 1;
        if (kb < 7) {
            STAGE6(cur ^ 1, kb + 1);
            asm volatile("s_waitcnt vmcnt(8)" ::: "memory");
        } else {
            asm volatile("s_waitcnt vmcnt(0)" ::: "memory");
        }
        __builtin_amdgcn_s_barrier();
        #pragma unroll
        for (int ks = 0; ks < 2; ks++) {
            int colA = ch0 ^ (ks << 5);
            short8 af[4], bfr[4];
            #pragma unroll
            for (int i = 0; i < 4; i++)
                af[i] = *(const short8*)&la[cur][wr*64 + i*16 + lr][colA];
            #pragma unroll
            for (int j = 0; j < 4; j++)
                bfr[j] = *(const short8*)&lb[cur][wc*64 + j*16 + lr][colA];
            #pragma unroll
            for (int i = 0; i < 4; i++)
                #pragma unroll
                for (int j = 0; j < 4; j++)
                    acc[i][j] = __builtin_amdgcn_mfma_f32_16x16x32_bf16(af[i], bfr[j], acc[i][j], 0, 0, 0);
        }
        __builtin_amdgcn_s_barrier();
    }
#undef STAGE6
    #pragma unroll
    for (int j = 0; j < 4; j++) {
        int lglob = L0 + wc*64 + j*16 + lr;
        float dt = dvec[(size_t)b * LL + lglob];
        float tailor = 1.0f / (512.0f + dt);
        #pragma unroll
        for (int i = 0; i < 4; i++) {
            int m4 = M0 + wr*64 + i*16 + q4*4;
            size_t ofs = ((size_t)b * LL + lglob) * HE + m4;
            ushort4 rv = *(const ushort4*)(Vb + ((size_t)b * LL + lglob) * HE + m4);
            float4 vs = *(const float4*)(sumV + (size_t)b * HE + m4);
            float4 o;
            o.x = bf2f(rv.x) + gma * (vs.x + acc[i][j][0]) * tailor;
            o.y = bf2f(rv.y) + gma * (vs.y + acc[i][j][1]) * tailor;
            o.z = bf2f(rv.z) + gma * (vs.z + acc[i][j][2]) * tailor;
            o.w = bf2f(rv.w) + gma * (vs.w + acc[i][j][3]) * tailor;
            *(float4*)(out + ofs) = o;
        }
    }
}

extern "C" void kernel_launch(void* const* d_in, const int* in_sizes, int n_in,
                              void* d_out, int out_size, void* d_ws, size_t ws_size,
                              hipStream_t stream) {
    const float* q     = (const float*)d_in[0];
    const float* gamma = (const float*)d_in[4];
    float* out = (float*)d_out;
    char* ws = (char*)d_ws;
    // ws layout (~177 MiB; proven to fit)
    float* sumV  = (float*)(ws);                          // 32 KiB
    float* cvec  = (float*)(ws + 65536);                  // 32 KiB
    float* invn  = (float*)(ws + 98304);                  // 32 KiB
    float* dvec  = (float*)(ws + 131072);                 // 256 KiB
    unsigned short* KQb = (unsigned short*)(ws + 524288);      // 8 MiB
    unsigned short* Vt  = (unsigned short*)(ws + 8912896);     // 64 MiB
    unsigned short* Vb  = (unsigned short*)(ws + 76021760);    // 64 MiB
    unsigned short* Gp  = (unsigned short*)(ws + 143130624);   // 40 MiB
    // stat partials live in d_out's head (8 MiB), consumed by k2 before k6
    float* ps = (float*)d_out;                            // 4 MiB (16 x 128 x 512)
    float* pq = (float*)d_out + 1048576;                  // 4 MiB

    k1_fuse4 <<<1024, 256, 0, stream>>>(q, Vb, Vt, ps, pq);
    k2_reduce<<<32,   256, 0, stream>>>(ps, pq, sumV, cvec, invn);
    k3_dvec  <<<2048, 256, 0, stream>>>(Vb, cvec, dvec);
    k4_gram  <<<1280, 256, 0, stream>>>(Vt, Gp);
    k5_reduce<<<160,  256, 0, stream>>>(Gp, invn, KQb);
    k6_part  <<<2048, 256, 0, stream>>>(KQb, Vb, dvec, sumV, gamma, out);
}